// Round 22
// baseline (159.159 us; speedup 1.0000x reference)
//
#include <hip/hip_runtime.h>
#include <math.h>

#define NPTS 1024
#define KNBR 20
#define CH 64

// ws layout (bytes): knn ushort [65536][20] @0; wp float[1024] @19398656;
// w2b @19402752; wqb @19410944; w1b @19443712

typedef __attribute__((ext_vector_type(8))) short s16x8;
typedef __attribute__((ext_vector_type(4))) float f32x4;

static __device__ __forceinline__ ushort f2bf(float f) {
  uint u = __float_as_uint(f);
  uint r = (u + 0x7FFFu + ((u >> 16) & 1u)) >> 16;
  return (ushort)r;
}

static __device__ __forceinline__ uint pkbf(float a, float b) {
  uint ua = __float_as_uint(a) + 0x8000u;
  uint ub = __float_as_uint(b) + 0x8000u;
  return __builtin_amdgcn_perm(ub, ua, 0x07060302);
}

static __device__ __forceinline__ int mbcnt64(unsigned long long m) {
  return __builtin_amdgcn_mbcnt_hi((uint)(m >> 32),
                                   __builtin_amdgcn_mbcnt_lo((uint)m, 0));
}

// ---------------- KNN + folded prep; 4-way paired u20/jr bisects ------------
__global__ __launch_bounds__(256) void k_knn(
    const float4* __restrict__ xv, ushort* __restrict__ knn,
    float4* __restrict__ outx, const float* __restrict__ Wh,
    const float* __restrict__ W1, const float* __restrict__ g1,
    const float* __restrict__ b1, const float* __restrict__ Wv,
    const float* __restrict__ Wk, const float* __restrict__ W2,
    const float* __restrict__ Wq, float* __restrict__ wp,
    ushort* __restrict__ w2b, ushort* __restrict__ wqb,
    ushort* __restrict__ w1b) {
  __shared__ float4 sx[NPTS];
  __shared__ float ssq[NPTS];
  __shared__ uint s_sk[4][64];
  __shared__ ushort s_sj[4][64];

  int t = threadIdx.x;
  int b = blockIdx.x >> 6, grp = blockIdx.x & 63;
  for (int j = t; j < NPTS; j += 256) {
    float4 p = xv[b * NPTS + j];
    sx[j] = p;
    ssq[j] = p.x * p.x + p.y * p.y + p.z * p.z + p.w * p.w;
    if (grp == 0) outx[b * NPTS + j] = p;  // folded k_copy (out0 = x)
  }
  __syncthreads();

  int w = t >> 6, l = t & 63;

  uint uk0 = 0xFFFFFFFFu, uj0 = 0xFFFFu;
  uint uk1 = 0xFFFFFFFFu, uj1 = 0xFFFFu;
  uint uk2 = 0xFFFFFFFFu, uj2 = 0xFFFFu;
  uint uk3 = 0xFFFFFFFFu, uj3 = 0xFFFFu;
  uint doneMask = 0;

  // per-center scan + T0 + compact (sequential: u[16] regs never doubled);
  // uk/uj read immediately after each compact (same-wave DS ordering),
  // then parked in named registers for the 4-way paired bisects.
  #pragma unroll 1
  for (int cc = 0; cc < 4; ++cc) {
    int cloc = grp * 16 + w * 4 + cc;
    int gid20 = (b * NPTS + cloc) * KNBR;
    float4 c = sx[cloc];
    uint u[16];
    uint mn = 0xFFFFFFFFu;
    #pragma unroll
    for (int s = 0; s < 16; ++s) {
      int j = s * 64 + l;
      float4 q = sx[j];
      float dot = c.x * q.x;
      dot = fmaf(c.y, q.y, dot);
      dot = fmaf(c.z, q.z, dot);
      dot = fmaf(c.w, q.w, dot);
      float key = fmaf(-2.f, dot, ssq[j]);
      uint uu = __float_as_uint(key);
      uu = ((int)uu < 0) ? ~uu : (uu | 0x80000000u);
      u[s] = uu;
      mn = min(mn, uu);
    }

    uint T0 = 0;
    #pragma unroll
    for (int bit = 31; bit >= 0; --bit) {
      uint cand = T0 | (1u << bit);
      if (__popcll(__ballot(mn < cand)) < 20) T0 = cand;
    }

    int base = 0;
    #pragma unroll
    for (int s = 0; s < 16; ++s) {
      unsigned long long mask = __ballot(u[s] <= T0);
      if (u[s] <= T0) {
        int off = base + mbcnt64(mask);
        if (off < 64) {
          s_sk[w][off] = u[s];
          s_sj[w][off] = (ushort)(s * 64 + l);
        }
      }
      base += (int)__popcll(mask);
    }
    int scnt = base;

    uint ukx = 0xFFFFFFFFu, ujx = 0xFFFFu;
    bool donex = false;
    if (scnt <= 64) {
      asm volatile("s_waitcnt lgkmcnt(0)" ::: "memory");
      __builtin_amdgcn_sched_barrier(0);
      ukx = (l < scnt) ? s_sk[w][l] : 0xFFFFFFFFu;
      ujx = (l < scnt) ? (uint)s_sj[w][l] : 0xFFFFu;
    } else {
      // exact fallback on full per-lane key set (rare); u[] still live
      uint u20 = 0;
      #pragma unroll 1
      for (int bit = 31; bit >= 0; --bit) {
        uint cand = u20 | (1u << bit);
        int cnt2 = 0;
        #pragma unroll
        for (int s = 0; s < 16; ++s)
          cnt2 += (int)__popcll(__ballot(u[s] < cand));
        if (cnt2 < 20) u20 = cand;
      }
      int base2 = 0;
      #pragma unroll
      for (int s = 0; s < 16; ++s) {
        unsigned long long mask = __ballot(u[s] < u20);
        if (u[s] < u20)
          knn[gid20 + base2 + mbcnt64(mask)] = (ushort)(s * 64 + l);
        base2 += (int)__popcll(mask);
      }
      int r = 20 - base2;
      #pragma unroll
      for (int s = 0; s < 16; ++s) {
        unsigned long long mask = __ballot(u[s] == u20);
        int pos = mbcnt64(mask);
        int cntm = (int)__popcll(mask);
        int take = (r < cntm) ? r : cntm;
        if ((u[s] == u20) && (pos < take))
          knn[gid20 + base2 + pos] = (ushort)(s * 64 + l);
        base2 += take;
        r -= take;
      }
      donex = true;
    }
    if (cc == 0) { uk0 = ukx; uj0 = ujx; }
    else if (cc == 1) { uk1 = ukx; uj1 = ujx; }
    else if (cc == 2) { uk2 = ukx; uj2 = ujx; }
    else { uk3 = ukx; uj3 = ujx; }
    if (donex) doneMask |= (1u << cc);
  }

  // 4-way paired u20 bisect (four independent serial chains overlapped)
  uint ua = 0, ub = 0, uc = 0, ud = 0;
  #pragma unroll
  for (int bit = 31; bit >= 0; --bit) {
    uint ca = ua | (1u << bit);
    uint cb = ub | (1u << bit);
    uint cn = uc | (1u << bit);
    uint cd = ud | (1u << bit);
    int na = (int)__popcll(__ballot(uk0 < ca));
    int nb = (int)__popcll(__ballot(uk1 < cb));
    int nc = (int)__popcll(__ballot(uk2 < cn));
    int nd = (int)__popcll(__ballot(uk3 < cd));
    if (na < 20) ua = ca;
    if (nb < 20) ub = cb;
    if (nc < 20) uc = cn;
    if (nd < 20) ud = cd;
  }
  int ma = (int)__popcll(__ballot(uk0 < ua));
  int mb = (int)__popcll(__ballot(uk1 < ub));
  int mc = (int)__popcll(__ballot(uk2 < uc));
  int md = (int)__popcll(__ballot(uk3 < ud));
  int ra = 20 - ma, rb = 20 - mb, rc = 20 - mc, rd = 20 - md;
  uint ja = 0, jb = 0, jc = 0, jd = 0;
  #pragma unroll
  for (int bit = 10; bit >= 0; --bit) {
    uint ca = ja | (1u << bit);
    uint cb = jb | (1u << bit);
    uint cn = jc | (1u << bit);
    uint cd = jd | (1u << bit);
    int na = (int)__popcll(__ballot((uk0 == ua) && (uj0 < ca)));
    int nb = (int)__popcll(__ballot((uk1 == ub) && (uj1 < cb)));
    int nc = (int)__popcll(__ballot((uk2 == uc) && (uj2 < cn)));
    int nd = (int)__popcll(__ballot((uk3 == ud) && (uj3 < cd)));
    if (na < ra) ja = ca;
    if (nb < rb) jb = cb;
    if (nc < rc) jc = cn;
    if (nd < rd) jd = cd;
  }
  {
    int gidBase = (b * NPTS + grp * 16 + w * 4) * KNBR;
    bool sA = (uk0 < ua) || ((uk0 == ua) && (uj0 <= ja));
    unsigned long long mA = __ballot(sA);
    if (!(doneMask & 1u) && sA) knn[gidBase + mbcnt64(mA)] = (ushort)uj0;
    bool sB = (uk1 < ub) || ((uk1 == ub) && (uj1 <= jb));
    unsigned long long mB = __ballot(sB);
    if (!(doneMask & 2u) && sB)
      knn[gidBase + KNBR + mbcnt64(mB)] = (ushort)uj1;
    bool sC = (uk2 < uc) || ((uk2 == uc) && (uj2 <= jc));
    unsigned long long mC = __ballot(sC);
    if (!(doneMask & 4u) && sC)
      knn[gidBase + 2 * KNBR + mbcnt64(mC)] = (ushort)uj2;
    bool sD = (uk3 < ud) || ((uk3 == ud) && (uj3 <= jd));
    unsigned long long mD = __ballot(sD);
    if (!(doneMask & 8u) && sD)
      knn[gidBase + 3 * KNBR + mbcnt64(mD)] = (ushort)uj3;
  }

  // ---- folded k_prep: block 1 only (block-uniform guard) ----
  if (blockIdx.x == 1) {
    {
      int o = t >> 2, c = t & 3;
      float acc = W1[o * 40 + c];
      #pragma unroll
      for (int v = 0; v < 32; ++v)
        acc = fmaf(W1[o * 40 + 8 + v], Wh[v * 4 + c], acc);
      float g = g1[o];
      wp[t] = g * acc;
      wp[256 + t] = g * W1[o * 40 + 4 + c];
    }
    if (t < 128) {
      int d = t >> 2, c = t & 3;
      float av = Wv[d * 40 + c];
      float ak = Wk[d * 40 + c];
      #pragma unroll
      for (int u2 = 0; u2 < 32; ++u2) {
        av = fmaf(Wv[d * 40 + 8 + u2], Wh[u2 * 4 + c], av);
        ak = fmaf(Wk[d * 40 + 8 + u2], Wh[u2 * 4 + c], ak);
      }
      wp[512 + t] = av;
      wp[640 + t] = Wv[d * 40 + 4 + c];
      wp[768 + t] = ak;
      wp[896 + t] = Wk[d * 40 + 4 + c];
    }
    #pragma unroll
    for (int i = 0; i < 16; ++i) w2b[t * 16 + i] = f2bf(W2[t * 16 + i]);
    for (int i = 0; i < 64; ++i) wqb[t * 64 + i] = f2bf(Wq[t * 64 + i]);
    __syncthreads();
    for (int idx = t; idx < 2048; idx += 256) {
      int ch = idx >> 5, kk = idx & 31;
      float v = 0.f;
      if (kk < 4) v = wp[ch * 4 + kk];
      else if (kk < 8) v = wp[256 + ch * 4 + (kk - 4)];
      else if (kk == 8) v = b1[ch];
      w1b[idx] = f2bf(v);
    }
  }
}

// ---------------- fused fq+attn: 16-point block (R21 verbatim) --------------
__global__ __launch_bounds__(256) void k_fused(
    const float4* __restrict__ xv, const ushort* __restrict__ knn,
    const float* __restrict__ wp, const ushort* __restrict__ w1b,
    const ushort* __restrict__ w2b, const ushort* __restrict__ wqb,
    const float* __restrict__ g2, const float* __restrict__ b2,
    const float* __restrict__ gq, const float* __restrict__ bq,
    const float* __restrict__ gv, const float* __restrict__ bv,
    float* __restrict__ o1) {
  __shared__ __align__(16) char smem[51200];
  char* s_h1 = smem;
  ushort* s_qb = (ushort*)smem;
  ushort* s_eb = (ushort*)(smem + 10496);
  float* s_out = (float*)(smem + 10496);
  float4* s_rel = (float4*)(smem + 40960);
  char* s_fqb = smem + 46080;
  float4* s_ctr = (float4*)(smem + 48384);
  ushort* s_ab = (ushort*)(smem + 40960);

  int t = threadIdx.x;
  int gid0 = blockIdx.x * 16;
  int bbase = (gid0 >> 10) << 10;
  int b = gid0 >> 10;
  int n0 = gid0 & 1023;
  int w = t >> 6, l = t & 63;
  int g = l >> 4, lane16 = l & 15;

  // ---- stage: ctr + rel ----
  if (t < 16) s_ctr[t] = xv[gid0 + t];
  #pragma unroll
  for (int it2 = 0; it2 < 2; ++it2) {
    int idx = t + it2 * 256;
    if (idx < 320) {
      int p = (int)(((uint)idx * 3277u) >> 16);
      int k = idx - p * 20;
      int nb = (int)knn[(size_t)(gid0 + p) * KNBR + k];
      float4 nx = xv[bbase + nb];
      float4 ct = xv[gid0 + p];
      s_rel[p * 20 + k] =
          make_float4(nx.x - ct.x, nx.y - ct.y, nx.z - ct.z, nx.w - ct.w);
    }
  }
  __syncthreads();

  // ---- h1-MFMA ----
  {
    s16x8 ah[4];
    #pragma unroll
    for (int m = 0; m < 4; ++m)
      ah[m] = *(const s16x8*)(w1b + (m * 16 + lane16) * 32 + g * 8);
    s16x8 bz = {0, 0, 0, 0, 0, 0, 0, 0};
    s16x8 bone = bz;
    bone[0] = (short)0x3F80;  // bf16(1.0) at K-slot 8
    #pragma unroll
    for (int q = 0; q < 5; ++q) {
      int col = w * 80 + q * 16 + lane16;  // p = lane16, kk = 5w + q
      s16x8 bf;
      if (g == 0) {
        float4 r = s_rel[lane16 * 20 + 5 * w + q];
        float4 ct = s_ctr[lane16];
        union { uint4 u; s16x8 s; } cv;
        cv.u.x = pkbf(r.x, r.y);
        cv.u.y = pkbf(r.z, r.w);
        cv.u.z = pkbf(ct.x, ct.y);
        cv.u.w = pkbf(ct.z, ct.w);
        bf = cv.s;
      } else {
        bf = (g == 1) ? bone : bz;
      }
      int swz = (col & 7) << 4;
      #pragma unroll
      for (int m = 0; m < 4; ++m) {
        f32x4 acc = {0.f, 0.f, 0.f, 0.f};
        acc = __builtin_amdgcn_mfma_f32_16x16x32_bf16(ah[m], bf, acc, 0, 0, 0);
        uint2 hv;
        hv.x = pkbf(fmaxf(acc[0], 0.f), fmaxf(acc[1], 0.f));
        hv.y = pkbf(fmaxf(acc[2], 0.f), fmaxf(acc[3], 0.f));
        int byteoff = col * 128 + (m * 16 + g * 4) * 2;
        *(uint2*)(s_h1 + (byteoff ^ swz)) = hv;
      }
    }
  }
  __syncthreads();

  // ---- W2-MFMA + maxpool -> s_fqb ----
  {
    int row0 = w * 16 + g * 4;
    s16x8 af0 = *(const s16x8*)(w2b + (w * 16 + lane16) * 64 + g * 8);
    s16x8 af1 = *(const s16x8*)(w2b + (w * 16 + lane16) * 64 + 32 + g * 8);
    float4 g2v = *(const float4*)(g2 + row0);
    float4 b2v = *(const float4*)(b2 + row0);
    float mx0 = 0.f, mx1 = 0.f, mx2 = 0.f, mx3 = 0.f;
    #pragma unroll 4
    for (int kt = 0; kt < 20; ++kt) {
      int col = kt * 16 + lane16;
      int rowbyte = col * 128;
      int swz = (col & 7) << 4;
      s16x8 bf0 = *(const s16x8*)(s_h1 + ((rowbyte + g * 16) ^ swz));
      s16x8 bf1 = *(const s16x8*)(s_h1 + ((rowbyte + 64 + g * 16) ^ swz));
      f32x4 acc = {0.f, 0.f, 0.f, 0.f};
      acc = __builtin_amdgcn_mfma_f32_16x16x32_bf16(af0, bf0, acc, 0, 0, 0);
      acc = __builtin_amdgcn_mfma_f32_16x16x32_bf16(af1, bf1, acc, 0, 0, 0);
      mx0 = fmaxf(mx0, fmaxf(fmaf(g2v.x, acc[0], b2v.x), 0.f));
      mx1 = fmaxf(mx1, fmaxf(fmaf(g2v.y, acc[1], b2v.y), 0.f));
      mx2 = fmaxf(mx2, fmaxf(fmaf(g2v.z, acc[2], b2v.z), 0.f));
      mx3 = fmaxf(mx3, fmaxf(fmaf(g2v.w, acc[3], b2v.w), 0.f));
    }
    uint2 u2;
    u2.x = pkbf(mx0, mx1);
    u2.y = pkbf(mx2, mx3);
    *(uint2*)(s_fqb + lane16 * 144 + row0 * 2) = u2;
  }
  __syncthreads();

  // ---- q-MFMA (16 cols) -> s_qb; ev -> s_eb + vv regs ----
  {
    s16x8 af[4][2];
    #pragma unroll
    for (int mm = 0; mm < 4; ++mm) {
      int row = w * 64 + mm * 16 + lane16;
      af[mm][0] = *(const s16x8*)(wqb + row * 64 + g * 8);
      af[mm][1] = *(const s16x8*)(wqb + row * 64 + 32 + g * 8);
    }
    s16x8 bf0 = *(const s16x8*)(s_fqb + lane16 * 144 + 0 * 64 + g * 16);
    s16x8 bf1 = *(const s16x8*)(s_fqb + lane16 * 144 + 1 * 64 + g * 16);
    #pragma unroll
    for (int mm = 0; mm < 4; ++mm) {
      f32x4 acc = {0.f, 0.f, 0.f, 0.f};
      acc = __builtin_amdgcn_mfma_f32_16x16x32_bf16(af[mm][0], bf0, acc, 0, 0, 0);
      acc = __builtin_amdgcn_mfma_f32_16x16x32_bf16(af[mm][1], bf1, acc, 0, 0, 0);
      int rbase = w * 64 + mm * 16 + g * 4;
      int h = rbase >> 5, d0 = rbase & 31;
      float4 gqv = *(const float4*)(gq + rbase);
      float4 bqv = *(const float4*)(bq + rbase);
      float v0 = fmaxf(fmaf(gqv.x, acc[0], bqv.x), 0.f);
      float v1 = fmaxf(fmaf(gqv.y, acc[1], bqv.y), 0.f);
      float v2 = fmaxf(fmaf(gqv.z, acc[2], bqv.z), 0.f);
      float v3 = fmaxf(fmaf(gqv.w, acc[3], bqv.w), 0.f);
      uint2 u2;
      u2.x = pkbf(v0, v1);
      u2.y = pkbf(v2, v3);
      *(uint2*)(s_qb + lane16 * 328 + h * 40 + d0) = u2;
    }
  }

  uint vp[2][10];
  {
    int d = t & 31, phalf = t >> 5;
    float4 wr = *(const float4*)(wp + 512 + 256 + d * 4);  // Wkr
    float4 wc = *(const float4*)(wp + 512 + 384 + d * 4);  // Wkc
    float4 vr_ = *(const float4*)(wp + 512 + 0 + d * 4);   // Wvr
    float4 vc_ = *(const float4*)(wp + 512 + 128 + d * 4); // Wvc
    float gvd = gv[d], bvd = bv[d];
    #pragma unroll
    for (int i = 0; i < 2; ++i) {
      int p = phalf + 8 * i;
      float4 ct = s_ctr[p];
      float cb = fmaf(wc.x, ct.x, fmaf(wc.y, ct.y, fmaf(wc.z, ct.z, wc.w * ct.w)));
      float ev[KNBR];
      float sum = 0.f;
      #pragma unroll
      for (int k = 0; k < KNBR; ++k) {
        float4 r = s_rel[p * 20 + k];
        float kkv =
            fmaf(wr.x, r.x, fmaf(wr.y, r.y, fmaf(wr.z, r.z, fmaf(wr.w, r.w, cb))));
        ev[k] = __expf(kkv);
        sum += ev[k];
      }
      float cbv = fmaf(vc_.x, ct.x, fmaf(vc_.y, ct.y, fmaf(vc_.z, ct.z, vc_.w * ct.w)));
      float vv[KNBR];
      #pragma unroll
      for (int k = 0; k < KNBR; ++k) {
        float4 r = s_rel[p * 20 + k];
        float raw =
            fmaf(vr_.x, r.x, fmaf(vr_.y, r.y, fmaf(vr_.z, r.z, fmaf(vr_.w, r.w, cbv))));
        vv[k] = fmaf(gvd, raw, bvd);
      }
      float rs = 1.0f / sum;
      #pragma unroll
      for (int k = 0; k < KNBR; ++k)
        s_eb[(p * 20 + k) * 40 + d] = f2bf(ev[k] * rs);
      #pragma unroll
      for (int k2 = 0; k2 < 10; ++k2) vp[i][k2] = pkbf(vv[k2 * 2], vv[k2 * 2 + 1]);
    }
  }
  __syncthreads();

  // ---- a-MFMA: wave w owns points {2w, 2w+1, 2w+8, 2w+9} ----
  #pragma unroll
  for (int pi2 = 0; pi2 < 4; ++pi2) {
    int plo = pi2 & 1, ii = pi2 >> 1;
    int pi = 2 * w + plo + 8 * ii;
    s16x8 qa = *(const s16x8*)(s_qb + pi * 328 + (lane16 & 7) * 40 + g * 8);
    #pragma unroll
    for (int tile = 0; tile < 2; ++tile) {
      int k = tile * 16 + lane16;
      int kc = (k < KNBR) ? k : (KNBR - 1);
      s16x8 eb = *(const s16x8*)(s_eb + (pi * 20 + kc) * 40 + g * 8);
      f32x4 acc = {0.f, 0.f, 0.f, 0.f};
      acc = __builtin_amdgcn_mfma_f32_16x16x32_bf16(qa, eb, acc, 0, 0, 0);
      if (g < 2) {
        if (k < KNBR) {
          #pragma unroll
          for (int r = 0; r < 4; ++r)
            s_ab[pi * 320 + (g * 4 + r) * 40 + k] = f2bf(acc[r]);
        } else {
          #pragma unroll
          for (int r = 0; r < 4; ++r) s_ab[pi * 320 + (g * 4 + r) * 40 + k] = 0;
        }
      }
    }
  }
  // no barrier: s_ab[pi] produced and consumed by the same wave (verified R19)

  // ---- out-MFMA: B-frag vv via intra-wave ds_bpermute ----
  #pragma unroll
  for (int pi2 = 0; pi2 < 4; ++pi2) {
    int plo = pi2 & 1, ii = pi2 >> 1;
    int pi = 2 * w + plo + 8 * ii;
    s16x8 aa = *(const s16x8*)(s_ab + pi * 320 + (lane16 & 7) * 40 + g * 8);
    #pragma unroll
    for (int vt = 0; vt < 2; ++vt) {
      int srcl4 = ((plo * 32 + vt * 16 + lane16) << 2);
      uint bu[4];
      #pragma unroll
      for (int i = 0; i < 4; ++i) {
        uint t0 = (uint)__builtin_amdgcn_ds_bpermute(srcl4, (int)vp[ii][i]);
        uint t1 = (uint)__builtin_amdgcn_ds_bpermute(srcl4, (int)vp[ii][4 + i]);
        uint t2 = (i < 2)
                      ? (uint)__builtin_amdgcn_ds_bpermute(srcl4, (int)vp[ii][8 + i])
                      : 0u;
        bu[i] = (g == 0) ? t0 : (g == 1) ? t1 : (g == 2) ? t2 : 0u;
      }
      union { uint4 u; s16x8 s; } bb;
      bb.u.x = bu[0]; bb.u.y = bu[1]; bb.u.z = bu[2]; bb.u.w = bu[3];
      f32x4 acc = {0.f, 0.f, 0.f, 0.f};
      acc = __builtin_amdgcn_mfma_f32_16x16x32_bf16(aa, bb.s, acc, 0, 0, 0);
      if (g < 2) {
        int v = vt * 16 + lane16;
        #pragma unroll
        for (int r = 0; r < 4; ++r) {
          int h = g * 4 + r;
          s_out[(h * 32 + v) * 17 + pi] = acc[r];
        }
      }
    }
  }
  __syncthreads();

  // ---- epilogue: 16 consecutive floats per 16-lane group (64B segments) ----
  #pragma unroll
  for (int e = 0; e < 16; ++e) {
    int idx = t + e * 256;
    int hv = idx >> 4, pp = idx & 15;
    o1[b * 262144 + hv * 1024 + n0 + pp] = s_out[hv * 17 + pp];
  }
}

extern "C" void kernel_launch(void* const* d_in, const int* in_sizes, int n_in,
                              void* d_out, int out_size, void* d_ws, size_t ws_size,
                              hipStream_t stream) {
  const float* x = (const float*)d_in[0];
  const float* Wh = (const float*)d_in[1];
  const float* W1 = (const float*)d_in[2];
  const float* g1 = (const float*)d_in[3];
  const float* b1 = (const float*)d_in[4];
  const float* W2 = (const float*)d_in[5];
  const float* g2 = (const float*)d_in[6];
  const float* b2 = (const float*)d_in[7];
  const float* Wv = (const float*)d_in[8];
  const float* gv = (const float*)d_in[9];
  const float* bv = (const float*)d_in[10];
  const float* Wk = (const float*)d_in[11];
  const float* Wq = (const float*)d_in[12];
  const float* gq = (const float*)d_in[13];
  const float* bq = (const float*)d_in[14];
  float* out = (float*)d_out;

  ushort* knn = (ushort*)d_ws;
  float* wp = (float*)((char*)d_ws + 19398656);
  ushort* w2b = (ushort*)((char*)d_ws + 19402752);
  ushort* wqb = (ushort*)((char*)d_ws + 19410944);
  ushort* w1b = (ushort*)((char*)d_ws + 19443712);

  hipLaunchKernelGGL(k_knn, dim3(4096), dim3(256), 0, stream, (const float4*)x, knn,
                     (float4*)out, Wh, W1, g1, b1, Wv, Wk, W2, Wq, wp, w2b, wqb,
                     w1b);
  hipLaunchKernelGGL(k_fused, dim3(4096), dim3(256), 0, stream, (const float4*)x,
                     knn, wp, w1b, w2b, wqb, g2, b2, gq, bq, gv, bv, out + 262144);
}

// Round 23
// 152.720 us; speedup vs baseline: 1.0422x; 1.0422x over previous
//
#include <hip/hip_runtime.h>
#include <math.h>

#define NPTS 1024
#define KNBR 20
#define CH 64

// ws layout (bytes): knn ushort [65536][20] @0; wp float[1024] @19398656;
// w2b @19402752; wqb @19410944; w1b @19443712

typedef __attribute__((ext_vector_type(8))) short s16x8;
typedef __attribute__((ext_vector_type(4))) float f32x4;

static __device__ __forceinline__ ushort f2bf(float f) {
  uint u = __float_as_uint(f);
  uint r = (u + 0x7FFFu + ((u >> 16) & 1u)) >> 16;
  return (ushort)r;
}

static __device__ __forceinline__ uint pkbf(float a, float b) {
  uint ua = __float_as_uint(a) + 0x8000u;
  uint ub = __float_as_uint(b) + 0x8000u;
  return __builtin_amdgcn_perm(ub, ua, 0x07060302);
}

static __device__ __forceinline__ int mbcnt64(unsigned long long m) {
  return __builtin_amdgcn_mbcnt_hi((uint)(m >> 32),
                                   __builtin_amdgcn_mbcnt_lo((uint)m, 0));
}

// ---------------- KNN + folded prep ----------------------------------------
// Pairing: per center-pair, scans/T0/compacts run sequentially (u[16] regs
// never doubled), then u20+jr bisects of both centers interleave so the two
// serial ballot chains overlap. Selection semantics bit-identical to R20.
__global__ __launch_bounds__(256) void k_knn(
    const float4* __restrict__ xv, ushort* __restrict__ knn,
    float4* __restrict__ outx, const float* __restrict__ Wh,
    const float* __restrict__ W1, const float* __restrict__ g1,
    const float* __restrict__ b1, const float* __restrict__ Wv,
    const float* __restrict__ Wk, const float* __restrict__ W2,
    const float* __restrict__ Wq, float* __restrict__ wp,
    ushort* __restrict__ w2b, ushort* __restrict__ wqb,
    ushort* __restrict__ w1b) {
  __shared__ float4 sx[NPTS];
  __shared__ float ssq[NPTS];
  __shared__ uint s_sk[4][64];
  __shared__ ushort s_sj[4][64];

  int t = threadIdx.x;
  int b = blockIdx.x >> 6, grp = blockIdx.x & 63;
  for (int j = t; j < NPTS; j += 256) {
    float4 p = xv[b * NPTS + j];
    sx[j] = p;
    ssq[j] = p.x * p.x + p.y * p.y + p.z * p.z + p.w * p.w;
    if (grp == 0) outx[b * NPTS + j] = p;  // folded k_copy (out0 = x)
  }
  __syncthreads();

  int w = t >> 6, l = t & 63;

  #pragma unroll 1
  for (int ip = 0; ip < 2; ++ip) {
    int c0 = grp * 16 + w * 4 + ip * 2;
    uint uk0 = 0xFFFFFFFFu, uj0 = 0xFFFFu, uk1 = 0xFFFFFFFFu, uj1 = 0xFFFFu;
    bool done0 = false, done1 = false;

    #pragma unroll
    for (int cc = 0; cc < 2; ++cc) {
      int cloc = c0 + cc;
      int gid20 = (b * NPTS + cloc) * KNBR;
      float4 c = sx[cloc];
      uint u[16];
      uint mn = 0xFFFFFFFFu;
      #pragma unroll
      for (int s = 0; s < 16; ++s) {
        int j = s * 64 + l;
        float4 q = sx[j];
        float dot = c.x * q.x;
        dot = fmaf(c.y, q.y, dot);
        dot = fmaf(c.z, q.z, dot);
        dot = fmaf(c.w, q.w, dot);
        float key = fmaf(-2.f, dot, ssq[j]);
        uint uu = __float_as_uint(key);
        uu = ((int)uu < 0) ? ~uu : (uu | 0x80000000u);
        u[s] = uu;
        mn = min(mn, uu);
      }

      uint T0 = 0;
      #pragma unroll
      for (int bit = 31; bit >= 0; --bit) {
        uint cand = T0 | (1u << bit);
        if (__popcll(__ballot(mn < cand)) < 20) T0 = cand;
      }

      // compact with clamped writes; scnt from the same ballots
      int base = 0;
      #pragma unroll
      for (int s = 0; s < 16; ++s) {
        unsigned long long mask = __ballot(u[s] <= T0);
        if (u[s] <= T0) {
          int off = base + mbcnt64(mask);
          if (off < 64) {
            s_sk[w][off] = u[s];
            s_sj[w][off] = (ushort)(s * 64 + l);
          }
        }
        base += (int)__popcll(mask);
      }
      int scnt = base;

      uint ukx, ujx;
      bool donex = false;
      if (scnt <= 64) {
        asm volatile("s_waitcnt lgkmcnt(0)" ::: "memory");
        __builtin_amdgcn_sched_barrier(0);
        ukx = (l < scnt) ? s_sk[w][l] : 0xFFFFFFFFu;
        ujx = (l < scnt) ? (uint)s_sj[w][l] : 0xFFFFu;
      } else {
        // exact fallback on full per-lane key set (rare); u[] still live
        uint u20 = 0;
        #pragma unroll 1
        for (int bit = 31; bit >= 0; --bit) {
          uint cand = u20 | (1u << bit);
          int cnt2 = 0;
          #pragma unroll
          for (int s = 0; s < 16; ++s)
            cnt2 += (int)__popcll(__ballot(u[s] < cand));
          if (cnt2 < 20) u20 = cand;
        }
        int base2 = 0;
        #pragma unroll
        for (int s = 0; s < 16; ++s) {
          unsigned long long mask = __ballot(u[s] < u20);
          if (u[s] < u20)
            knn[gid20 + base2 + mbcnt64(mask)] = (ushort)(s * 64 + l);
          base2 += (int)__popcll(mask);
        }
        int r = 20 - base2;
        #pragma unroll
        for (int s = 0; s < 16; ++s) {
          unsigned long long mask = __ballot(u[s] == u20);
          int pos = mbcnt64(mask);
          int cntm = (int)__popcll(mask);
          int take = (r < cntm) ? r : cntm;
          if ((u[s] == u20) && (pos < take))
            knn[gid20 + base2 + pos] = (ushort)(s * 64 + l);
          base2 += take;
          r -= take;
        }
        donex = true;
        ukx = 0xFFFFFFFFu;
        ujx = 0xFFFFu;
      }
      if (cc == 0) {
        uk0 = ukx; uj0 = ujx; done0 = donex;
      } else {
        uk1 = ukx; uj1 = ujx; done1 = donex;
      }
    }

    // paired u20 bisect (two independent chains, latency overlapped)
    uint u20a = 0, u20b = 0;
    #pragma unroll
    for (int bit = 31; bit >= 0; --bit) {
      uint ca = u20a | (1u << bit);
      uint cb = u20b | (1u << bit);
      int na = (int)__popcll(__ballot(uk0 < ca));
      int nb = (int)__popcll(__ballot(uk1 < cb));
      if (na < 20) u20a = ca;
      if (nb < 20) u20b = cb;
    }
    int ma = (int)__popcll(__ballot(uk0 < u20a));
    int mb = (int)__popcll(__ballot(uk1 < u20b));
    int ra = 20 - ma, rb = 20 - mb;
    uint jra = 0, jrb = 0;
    #pragma unroll
    for (int bit = 10; bit >= 0; --bit) {
      uint ca = jra | (1u << bit);
      uint cb = jrb | (1u << bit);
      int na = (int)__popcll(__ballot((uk0 == u20a) && (uj0 < ca)));
      int nb = (int)__popcll(__ballot((uk1 == u20b) && (uj1 < cb)));
      if (na < ra) jra = ca;
      if (nb < rb) jrb = cb;
    }
    {
      int gidA = (b * NPTS + c0) * KNBR;
      bool selA = (uk0 < u20a) || ((uk0 == u20a) && (uj0 <= jra));
      unsigned long long smA = __ballot(selA);
      if (!done0 && selA) knn[gidA + mbcnt64(smA)] = (ushort)uj0;
      bool selB = (uk1 < u20b) || ((uk1 == u20b) && (uj1 <= jrb));
      unsigned long long smB = __ballot(selB);
      if (!done1 && selB) knn[gidA + KNBR + mbcnt64(smB)] = (ushort)uj1;
    }
  }

  // ---- folded k_prep: block 1 only (block-uniform guard) ----
  if (blockIdx.x == 1) {
    {
      int o = t >> 2, c = t & 3;
      float acc = W1[o * 40 + c];
      #pragma unroll
      for (int v = 0; v < 32; ++v)
        acc = fmaf(W1[o * 40 + 8 + v], Wh[v * 4 + c], acc);
      float g = g1[o];
      wp[t] = g * acc;
      wp[256 + t] = g * W1[o * 40 + 4 + c];
    }
    if (t < 128) {
      int d = t >> 2, c = t & 3;
      float av = Wv[d * 40 + c];
      float ak = Wk[d * 40 + c];
      #pragma unroll
      for (int u2 = 0; u2 < 32; ++u2) {
        av = fmaf(Wv[d * 40 + 8 + u2], Wh[u2 * 4 + c], av);
        ak = fmaf(Wk[d * 40 + 8 + u2], Wh[u2 * 4 + c], ak);
      }
      wp[512 + t] = av;
      wp[640 + t] = Wv[d * 40 + 4 + c];
      wp[768 + t] = ak;
      wp[896 + t] = Wk[d * 40 + 4 + c];
    }
    #pragma unroll
    for (int i = 0; i < 16; ++i) w2b[t * 16 + i] = f2bf(W2[t * 16 + i]);
    for (int i = 0; i < 64; ++i) wqb[t * 64 + i] = f2bf(Wq[t * 64 + i]);
    __syncthreads();
    for (int idx = t; idx < 2048; idx += 256) {
      int ch = idx >> 5, kk = idx & 31;
      float v = 0.f;
      if (kk < 4) v = wp[ch * 4 + kk];
      else if (kk < 8) v = wp[256 + ch * 4 + (kk - 4)];
      else if (kk == 8) v = b1[ch];
      w1b[idx] = f2bf(v);
    }
  }
}

// ---------------- fused fq+attn: 16-point block (R21 verbatim) --------------
__global__ __launch_bounds__(256) void k_fused(
    const float4* __restrict__ xv, const ushort* __restrict__ knn,
    const float* __restrict__ wp, const ushort* __restrict__ w1b,
    const ushort* __restrict__ w2b, const ushort* __restrict__ wqb,
    const float* __restrict__ g2, const float* __restrict__ b2,
    const float* __restrict__ gq, const float* __restrict__ bq,
    const float* __restrict__ gv, const float* __restrict__ bv,
    float* __restrict__ o1) {
  __shared__ __align__(16) char smem[51200];
  char* s_h1 = smem;
  ushort* s_qb = (ushort*)smem;
  ushort* s_eb = (ushort*)(smem + 10496);
  float* s_out = (float*)(smem + 10496);
  float4* s_rel = (float4*)(smem + 40960);
  char* s_fqb = smem + 46080;
  float4* s_ctr = (float4*)(smem + 48384);
  ushort* s_ab = (ushort*)(smem + 40960);

  int t = threadIdx.x;
  int gid0 = blockIdx.x * 16;
  int bbase = (gid0 >> 10) << 10;
  int b = gid0 >> 10;
  int n0 = gid0 & 1023;
  int w = t >> 6, l = t & 63;
  int g = l >> 4, lane16 = l & 15;

  // ---- stage: ctr + rel ----
  if (t < 16) s_ctr[t] = xv[gid0 + t];
  #pragma unroll
  for (int it2 = 0; it2 < 2; ++it2) {
    int idx = t + it2 * 256;
    if (idx < 320) {
      int p = (int)(((uint)idx * 3277u) >> 16);
      int k = idx - p * 20;
      int nb = (int)knn[(size_t)(gid0 + p) * KNBR + k];
      float4 nx = xv[bbase + nb];
      float4 ct = xv[gid0 + p];
      s_rel[p * 20 + k] =
          make_float4(nx.x - ct.x, nx.y - ct.y, nx.z - ct.z, nx.w - ct.w);
    }
  }
  __syncthreads();

  // ---- h1-MFMA ----
  {
    s16x8 ah[4];
    #pragma unroll
    for (int m = 0; m < 4; ++m)
      ah[m] = *(const s16x8*)(w1b + (m * 16 + lane16) * 32 + g * 8);
    s16x8 bz = {0, 0, 0, 0, 0, 0, 0, 0};
    s16x8 bone = bz;
    bone[0] = (short)0x3F80;  // bf16(1.0) at K-slot 8
    #pragma unroll
    for (int q = 0; q < 5; ++q) {
      int col = w * 80 + q * 16 + lane16;  // p = lane16, kk = 5w + q
      s16x8 bf;
      if (g == 0) {
        float4 r = s_rel[lane16 * 20 + 5 * w + q];
        float4 ct = s_ctr[lane16];
        union { uint4 u; s16x8 s; } cv;
        cv.u.x = pkbf(r.x, r.y);
        cv.u.y = pkbf(r.z, r.w);
        cv.u.z = pkbf(ct.x, ct.y);
        cv.u.w = pkbf(ct.z, ct.w);
        bf = cv.s;
      } else {
        bf = (g == 1) ? bone : bz;
      }
      int swz = (col & 7) << 4;
      #pragma unroll
      for (int m = 0; m < 4; ++m) {
        f32x4 acc = {0.f, 0.f, 0.f, 0.f};
        acc = __builtin_amdgcn_mfma_f32_16x16x32_bf16(ah[m], bf, acc, 0, 0, 0);
        uint2 hv;
        hv.x = pkbf(fmaxf(acc[0], 0.f), fmaxf(acc[1], 0.f));
        hv.y = pkbf(fmaxf(acc[2], 0.f), fmaxf(acc[3], 0.f));
        int byteoff = col * 128 + (m * 16 + g * 4) * 2;
        *(uint2*)(s_h1 + (byteoff ^ swz)) = hv;
      }
    }
  }
  __syncthreads();

  // ---- W2-MFMA + maxpool -> s_fqb ----
  {
    int row0 = w * 16 + g * 4;
    s16x8 af0 = *(const s16x8*)(w2b + (w * 16 + lane16) * 64 + g * 8);
    s16x8 af1 = *(const s16x8*)(w2b + (w * 16 + lane16) * 64 + 32 + g * 8);
    float4 g2v = *(const float4*)(g2 + row0);
    float4 b2v = *(const float4*)(b2 + row0);
    float mx0 = 0.f, mx1 = 0.f, mx2 = 0.f, mx3 = 0.f;
    #pragma unroll 4
    for (int kt = 0; kt < 20; ++kt) {
      int col = kt * 16 + lane16;
      int rowbyte = col * 128;
      int swz = (col & 7) << 4;
      s16x8 bf0 = *(const s16x8*)(s_h1 + ((rowbyte + g * 16) ^ swz));
      s16x8 bf1 = *(const s16x8*)(s_h1 + ((rowbyte + 64 + g * 16) ^ swz));
      f32x4 acc = {0.f, 0.f, 0.f, 0.f};
      acc = __builtin_amdgcn_mfma_f32_16x16x32_bf16(af0, bf0, acc, 0, 0, 0);
      acc = __builtin_amdgcn_mfma_f32_16x16x32_bf16(af1, bf1, acc, 0, 0, 0);
      mx0 = fmaxf(mx0, fmaxf(fmaf(g2v.x, acc[0], b2v.x), 0.f));
      mx1 = fmaxf(mx1, fmaxf(fmaf(g2v.y, acc[1], b2v.y), 0.f));
      mx2 = fmaxf(mx2, fmaxf(fmaf(g2v.z, acc[2], b2v.z), 0.f));
      mx3 = fmaxf(mx3, fmaxf(fmaf(g2v.w, acc[3], b2v.w), 0.f));
    }
    uint2 u2;
    u2.x = pkbf(mx0, mx1);
    u2.y = pkbf(mx2, mx3);
    *(uint2*)(s_fqb + lane16 * 144 + row0 * 2) = u2;
  }
  __syncthreads();

  // ---- q-MFMA (16 cols) -> s_qb; ev -> s_eb + vv regs ----
  {
    s16x8 af[4][2];
    #pragma unroll
    for (int mm = 0; mm < 4; ++mm) {
      int row = w * 64 + mm * 16 + lane16;
      af[mm][0] = *(const s16x8*)(wqb + row * 64 + g * 8);
      af[mm][1] = *(const s16x8*)(wqb + row * 64 + 32 + g * 8);
    }
    s16x8 bf0 = *(const s16x8*)(s_fqb + lane16 * 144 + 0 * 64 + g * 16);
    s16x8 bf1 = *(const s16x8*)(s_fqb + lane16 * 144 + 1 * 64 + g * 16);
    #pragma unroll
    for (int mm = 0; mm < 4; ++mm) {
      f32x4 acc = {0.f, 0.f, 0.f, 0.f};
      acc = __builtin_amdgcn_mfma_f32_16x16x32_bf16(af[mm][0], bf0, acc, 0, 0, 0);
      acc = __builtin_amdgcn_mfma_f32_16x16x32_bf16(af[mm][1], bf1, acc, 0, 0, 0);
      int rbase = w * 64 + mm * 16 + g * 4;
      int h = rbase >> 5, d0 = rbase & 31;
      float4 gqv = *(const float4*)(gq + rbase);
      float4 bqv = *(const float4*)(bq + rbase);
      float v0 = fmaxf(fmaf(gqv.x, acc[0], bqv.x), 0.f);
      float v1 = fmaxf(fmaf(gqv.y, acc[1], bqv.y), 0.f);
      float v2 = fmaxf(fmaf(gqv.z, acc[2], bqv.z), 0.f);
      float v3 = fmaxf(fmaf(gqv.w, acc[3], bqv.w), 0.f);
      uint2 u2;
      u2.x = pkbf(v0, v1);
      u2.y = pkbf(v2, v3);
      *(uint2*)(s_qb + lane16 * 328 + h * 40 + d0) = u2;
    }
  }

  uint vp[2][10];
  {
    int d = t & 31, phalf = t >> 5;
    float4 wr = *(const float4*)(wp + 512 + 256 + d * 4);  // Wkr
    float4 wc = *(const float4*)(wp + 512 + 384 + d * 4);  // Wkc
    float4 vr_ = *(const float4*)(wp + 512 + 0 + d * 4);   // Wvr
    float4 vc_ = *(const float4*)(wp + 512 + 128 + d * 4); // Wvc
    float gvd = gv[d], bvd = bv[d];
    #pragma unroll
    for (int i = 0; i < 2; ++i) {
      int p = phalf + 8 * i;
      float4 ct = s_ctr[p];
      float cb = fmaf(wc.x, ct.x, fmaf(wc.y, ct.y, fmaf(wc.z, ct.z, wc.w * ct.w)));
      float ev[KNBR];
      float sum = 0.f;
      #pragma unroll
      for (int k = 0; k < KNBR; ++k) {
        float4 r = s_rel[p * 20 + k];
        float kkv =
            fmaf(wr.x, r.x, fmaf(wr.y, r.y, fmaf(wr.z, r.z, fmaf(wr.w, r.w, cb))));
        ev[k] = __expf(kkv);
        sum += ev[k];
      }
      float cbv = fmaf(vc_.x, ct.x, fmaf(vc_.y, ct.y, fmaf(vc_.z, ct.z, vc_.w * ct.w)));
      float vv[KNBR];
      #pragma unroll
      for (int k = 0; k < KNBR; ++k) {
        float4 r = s_rel[p * 20 + k];
        float raw =
            fmaf(vr_.x, r.x, fmaf(vr_.y, r.y, fmaf(vr_.z, r.z, fmaf(vr_.w, r.w, cbv))));
        vv[k] = fmaf(gvd, raw, bvd);
      }
      float rs = 1.0f / sum;
      #pragma unroll
      for (int k = 0; k < KNBR; ++k)
        s_eb[(p * 20 + k) * 40 + d] = f2bf(ev[k] * rs);
      #pragma unroll
      for (int k2 = 0; k2 < 10; ++k2) vp[i][k2] = pkbf(vv[k2 * 2], vv[k2 * 2 + 1]);
    }
  }
  __syncthreads();

  // ---- a-MFMA: wave w owns points {2w, 2w+1, 2w+8, 2w+9} ----
  #pragma unroll
  for (int pi2 = 0; pi2 < 4; ++pi2) {
    int plo = pi2 & 1, ii = pi2 >> 1;
    int pi = 2 * w + plo + 8 * ii;
    s16x8 qa = *(const s16x8*)(s_qb + pi * 328 + (lane16 & 7) * 40 + g * 8);
    #pragma unroll
    for (int tile = 0; tile < 2; ++tile) {
      int k = tile * 16 + lane16;
      int kc = (k < KNBR) ? k : (KNBR - 1);
      s16x8 eb = *(const s16x8*)(s_eb + (pi * 20 + kc) * 40 + g * 8);
      f32x4 acc = {0.f, 0.f, 0.f, 0.f};
      acc = __builtin_amdgcn_mfma_f32_16x16x32_bf16(qa, eb, acc, 0, 0, 0);
      if (g < 2) {
        if (k < KNBR) {
          #pragma unroll
          for (int r = 0; r < 4; ++r)
            s_ab[pi * 320 + (g * 4 + r) * 40 + k] = f2bf(acc[r]);
        } else {
          #pragma unroll
          for (int r = 0; r < 4; ++r) s_ab[pi * 320 + (g * 4 + r) * 40 + k] = 0;
        }
      }
    }
  }
  // no barrier: s_ab[pi] produced and consumed by the same wave (verified R19)

  // ---- out-MFMA: B-frag vv via intra-wave ds_bpermute ----
  #pragma unroll
  for (int pi2 = 0; pi2 < 4; ++pi2) {
    int plo = pi2 & 1, ii = pi2 >> 1;
    int pi = 2 * w + plo + 8 * ii;
    s16x8 aa = *(const s16x8*)(s_ab + pi * 320 + (lane16 & 7) * 40 + g * 8);
    #pragma unroll
    for (int vt = 0; vt < 2; ++vt) {
      int srcl4 = ((plo * 32 + vt * 16 + lane16) << 2);
      uint bu[4];
      #pragma unroll
      for (int i = 0; i < 4; ++i) {
        uint t0 = (uint)__builtin_amdgcn_ds_bpermute(srcl4, (int)vp[ii][i]);
        uint t1 = (uint)__builtin_amdgcn_ds_bpermute(srcl4, (int)vp[ii][4 + i]);
        uint t2 = (i < 2)
                      ? (uint)__builtin_amdgcn_ds_bpermute(srcl4, (int)vp[ii][8 + i])
                      : 0u;
        bu[i] = (g == 0) ? t0 : (g == 1) ? t1 : (g == 2) ? t2 : 0u;
      }
      union { uint4 u; s16x8 s; } bb;
      bb.u.x = bu[0]; bb.u.y = bu[1]; bb.u.z = bu[2]; bb.u.w = bu[3];
      f32x4 acc = {0.f, 0.f, 0.f, 0.f};
      acc = __builtin_amdgcn_mfma_f32_16x16x32_bf16(aa, bb.s, acc, 0, 0, 0);
      if (g < 2) {
        int v = vt * 16 + lane16;
        #pragma unroll
        for (int r = 0; r < 4; ++r) {
          int h = g * 4 + r;
          s_out[(h * 32 + v) * 17 + pi] = acc[r];
        }
      }
    }
  }
  __syncthreads();

  // ---- epilogue: 16 consecutive floats per 16-lane group (64B segments) ----
  #pragma unroll
  for (int e = 0; e < 16; ++e) {
    int idx = t + e * 256;
    int hv = idx >> 4, pp = idx & 15;
    o1[b * 262144 + hv * 1024 + n0 + pp] = s_out[hv * 17 + pp];
  }
}

extern "C" void kernel_launch(void* const* d_in, const int* in_sizes, int n_in,
                              void* d_out, int out_size, void* d_ws, size_t ws_size,
                              hipStream_t stream) {
  const float* x = (const float*)d_in[0];
  const float* Wh = (const float*)d_in[1];
  const float* W1 = (const float*)d_in[2];
  const float* g1 = (const float*)d_in[3];
  const float* b1 = (const float*)d_in[4];
  const float* W2 = (const float*)d_in[5];
  const float* g2 = (const float*)d_in[6];
  const float* b2 = (const float*)d_in[7];
  const float* Wv = (const float*)d_in[8];
  const float* gv = (const float*)d_in[9];
  const float* bv = (const float*)d_in[10];
  const float* Wk = (const float*)d_in[11];
  const float* Wq = (const float*)d_in[12];
  const float* gq = (const float*)d_in[13];
  const float* bq = (const float*)d_in[14];
  float* out = (float*)d_out;

  ushort* knn = (ushort*)d_ws;
  float* wp = (float*)((char*)d_ws + 19398656);
  ushort* w2b = (ushort*)((char*)d_ws + 19402752);
  ushort* wqb = (ushort*)((char*)d_ws + 19410944);
  ushort* w1b = (ushort*)((char*)d_ws + 19443712);

  hipLaunchKernelGGL(k_knn, dim3(4096), dim3(256), 0, stream, (const float4*)x, knn,
                     (float4*)out, Wh, W1, g1, b1, Wv, Wk, W2, Wq, wp, w2b, wqb,
                     w1b);
  hipLaunchKernelGGL(k_fused, dim3(4096), dim3(256), 0, stream, (const float4*)x,
                     knn, wp, w1b, w2b, wqb, g2, b2, gq, bq, gv, bv, out + 262144);
}